// Round 7
// baseline (204.383 us; speedup 1.0000x reference)
//
#include <hip/hip_runtime.h>
#include <cstdint>

// B=16384 rows, K=2048 centers, D=128, T=1.0
// Outputs (flat, f32): out[B*D], center[K*D], label[B]
#define NB 16384
#define NK 2048
#define ND 128
#define MARGIN 0.10f
#define CAP 1024

typedef __attribute__((ext_vector_type(8))) short bf16x8;
typedef __attribute__((ext_vector_type(4))) float f32x4;
typedef unsigned long long u64;

__device__ __forceinline__ unsigned short f2bf(float f) {
    unsigned u = __float_as_uint(f);
    u += 0x7fffu + ((u >> 16) & 1u);          // round-to-nearest-even
    return (unsigned short)(u >> 16);
}

// Exact refine, R1-identical fp32 chain (serial fmaf dot, t=x2+c2,
// fmaf(-2,dot,t), max, sqrt; u64 key -> lowest k on tie).
__device__ __noinline__ void refine_one(const float* __restrict__ x,
                                        const float* __restrict__ center,
                                        const float* __restrict__ c2,
                                        const float* __restrict__ x2g,
                                        u64* __restrict__ partial,
                                        int row, int col) {
    const float* xr = x + (long)row * ND;
    const float* cr = center + (long)col * ND;
    float dot = 0.f;
#pragma unroll 8
    for (int d = 0; d < ND; ++d) dot = fmaf(xr[d], cr[d], dot);
    float t = x2g[row] + c2[col];
    float f = fmaxf(fmaf(-2.0f, dot, t), 0.0f);
    float s = __builtin_sqrtf(f);
    u64 key = ((u64)__float_as_uint(s) << 32) | (unsigned)col;
    atomicMin(&partial[row], key);
}

// ---------------------------------------------------------------------------
// Prep (5512 blocks):
//  [0,4096)    x2 (R1-identical butterfly) + partial init
//  [4096,5120) xbf: x -> bf16 MFMA A-frag layout (R4-verified)
//  [5120,5248) cbf: center -> bf16 MFMA B-frag layout (R4-verified)
//  [5248,5256) c2 (R1-identical chain)
//  [5256,5512) center passthrough copy
// ---------------------------------------------------------------------------
__global__ __launch_bounds__(256)
void prep(const float* __restrict__ x,
          const float* __restrict__ c,
          unsigned short* __restrict__ xbf,
          unsigned short* __restrict__ cbf,
          float* __restrict__ c2,
          float* __restrict__ x2,
          u64* __restrict__ partial,
          float* __restrict__ out_center) {
    const int bid = blockIdx.x;
    const int tid = threadIdx.x;
    if (bid < 4096) {
        const int row  = bid * 4 + (tid >> 6);
        const int lane = tid & 63;
        float2 v = ((const float2*)(x + (long)row * ND))[lane];
        float s = v.x * v.x + v.y * v.y;
#pragma unroll
        for (int off = 32; off; off >>= 1) s += __shfl_xor(s, off, 64);
        if (lane == 0) {
            x2[row] = s;
            partial[row] = ~0ULL;
        }
    } else if (bid < 5120) {
        int t = (bid - 4096) * 256 + tid;     // 0..262143
        int lane = t & 63, s = (t >> 6) & 3, rt = t >> 8;
        int row = rt * 16 + (lane & 15);
        int d0  = s * 32 + (lane >> 4) * 8;
        const float* src = x + (long)row * ND + d0;
        unsigned short h[8];
#pragma unroll
        for (int j = 0; j < 8; ++j) h[j] = f2bf(src[j]);
        int4 pk;
        pk.x = h[0] | (h[1] << 16); pk.y = h[2] | (h[3] << 16);
        pk.z = h[4] | (h[5] << 16); pk.w = h[6] | (h[7] << 16);
        ((int4*)xbf)[t] = pk;
    } else if (bid < 5248) {
        int t = (bid - 5120) * 256 + tid;     // 0..32767
        int lane = t & 63, s = (t >> 6) & 3, kt = t >> 8;
        int kc = kt * 16 + (lane & 15);
        int d0 = s * 32 + (lane >> 4) * 8;
        const float* src = c + (long)kc * ND + d0;
        unsigned short h[8];
#pragma unroll
        for (int j = 0; j < 8; ++j) h[j] = f2bf(src[j]);
        int4 pk;
        pk.x = h[0] | (h[1] << 16); pk.y = h[2] | (h[3] << 16);
        pk.z = h[4] | (h[5] << 16); pk.w = h[6] | (h[7] << 16);
        ((int4*)cbf)[t] = pk;
    } else if (bid < 5256) {
        int k = (bid - 5248) * 256 + tid;
        const float4* row = (const float4*)(c + (long)k * ND);
        float s = 0.f;
#pragma unroll 8
        for (int i = 0; i < ND / 4; ++i) {
            float4 v = row[i];
            s += v.x * v.x + v.y * v.y + v.z * v.z + v.w * v.w;
        }
        c2[k] = s;
    } else {
        int i = (bid - 5256) * 256 + tid;
        ((float4*)out_center)[i] = ((const float4*)c)[i];
    }
}

// ---------------------------------------------------------------------------
// Main: 2048 blocks (rg 0..127 x cg 0..15) x 256 threads. Block = 128 rows x
// 128 cols. B-tile (32KB cbf slice) staged once to LDS; wave holds 2 A-tiles
// in regs; inner loop = 32 ds_read_b128 + 64 MFMA, nothing else. Epilogue:
// block-min from live accs -> threshold -> collect from live accs -> exact
// refine -> global u64 atomicMin per row.
// ---------------------------------------------------------------------------
__global__ __launch_bounds__(256)
void kmeans_main(const unsigned short* __restrict__ xbf,
                 const unsigned short* __restrict__ cbf,
                 const float* __restrict__ c2,
                 const float* __restrict__ x2g,
                 const float* __restrict__ x,
                 const float* __restrict__ center,
                 u64* __restrict__ partial) {
    __shared__ int4 bsh[2048];                 // 32KB B-tile (linear cbf slice)
    __shared__ unsigned bmin[128];
    __shared__ unsigned buf[CAP];
    __shared__ unsigned cnt;

    const int tid  = threadIdx.x;
    const int lane = tid & 63;
    const int wave = __builtin_amdgcn_readfirstlane(tid >> 6);  // 0..3
    const int rg = blockIdx.x >> 4;            // row-group (128 rows)
    const int cg = blockIdx.x & 15;            // col-group (128 cols)

    // ---- stage B-tile: cbf[cg*16384 .. +16384) shorts, linear 32KB ----
    {
        const int4* src = (const int4*)cbf + cg * 2048;
#pragma unroll
        for (int i = 0; i < 8; ++i) bsh[tid + i * 256] = src[tid + i * 256];
    }
    if (tid < 128) bmin[tid] = 0x7f800000u;
    if (tid == 0) cnt = 0;

    // ---- A-frags (2 row-tiles) + scalars, while stage is in flight ----
    const bf16x8* XF = (const bf16x8*)xbf;
    const int rtg0 = rg * 8 + wave * 2;
    bf16x8 af[2][4];
#pragma unroll
    for (int rt = 0; rt < 2; ++rt)
#pragma unroll
        for (int s = 0; s < 4; ++s)
            af[rt][s] = XF[((rtg0 + rt) * 4 + s) * 64 + lane];

    float c2v[8];
#pragma unroll
    for (int ct = 0; ct < 8; ++ct)
        c2v[ct] = c2[cg * 128 + ct * 16 + (lane & 15)];

    float x2p[2][4];
#pragma unroll
    for (int rt = 0; rt < 2; ++rt)
#pragma unroll
        for (int reg = 0; reg < 4; ++reg)
            x2p[rt][reg] = x2g[rg * 128 + wave * 32 + rt * 16 + (lane >> 4) * 4 + reg];

    __syncthreads();

    // ---- inner loop: pure LDS + MFMA ----
    const bf16x8* BS = (const bf16x8*)bsh;
    f32x4 acc[2][8];
#pragma unroll
    for (int rt = 0; rt < 2; ++rt)
#pragma unroll
        for (int ct = 0; ct < 8; ++ct) acc[rt][ct] = (f32x4){0.f, 0.f, 0.f, 0.f};

#pragma unroll
    for (int ct = 0; ct < 8; ++ct)
#pragma unroll
        for (int s = 0; s < 4; ++s) {
            bf16x8 b = BS[(ct * 4 + s) * 64 + lane];
            acc[0][ct] = __builtin_amdgcn_mfma_f32_16x16x32_bf16(af[0][s], b, acc[0][ct], 0, 0, 0);
            acc[1][ct] = __builtin_amdgcn_mfma_f32_16x16x32_bf16(af[1][s], b, acc[1][ct], 0, 0, 0);
        }

    // ---- block-min per row (from live accs) ----
    float rmin[2][4];
#pragma unroll
    for (int rt = 0; rt < 2; ++rt)
#pragma unroll
        for (int reg = 0; reg < 4; ++reg) rmin[rt][reg] = __builtin_inff();
#pragma unroll
    for (int rt = 0; rt < 2; ++rt)
#pragma unroll
        for (int ct = 0; ct < 8; ++ct)
#pragma unroll
            for (int reg = 0; reg < 4; ++reg) {
                float d2 = fmaf(-2.f, acc[rt][ct][reg], x2p[rt][reg] + c2v[ct]);
                rmin[rt][reg] = fminf(rmin[rt][reg], d2);
            }
#pragma unroll
    for (int rt = 0; rt < 2; ++rt)
#pragma unroll
        for (int reg = 0; reg < 4; ++reg) {
            float v = rmin[rt][reg];
#pragma unroll
            for (int off = 1; off < 16; off <<= 1)
                v = fminf(v, __shfl_xor(v, off, 64));
            if ((lane & 15) == 0)
                atomicMin(&bmin[wave * 32 + rt * 16 + (lane >> 4) * 4 + reg],
                          __float_as_uint(fmaxf(v, 0.f)));
        }
    __syncthreads();

    // ---- collect candidates (recompute d2 from live accs) ----
    float thr[2][4];
#pragma unroll
    for (int rt = 0; rt < 2; ++rt)
#pragma unroll
        for (int reg = 0; reg < 4; ++reg)
            thr[rt][reg] = __uint_as_float(
                bmin[wave * 32 + rt * 16 + (lane >> 4) * 4 + reg]) + MARGIN;

#pragma unroll
    for (int rt = 0; rt < 2; ++rt)
#pragma unroll
        for (int ct = 0; ct < 8; ++ct)
#pragma unroll
            for (int reg = 0; reg < 4; ++reg) {
                float d2 = fmaf(-2.f, acc[rt][ct][reg], x2p[rt][reg] + c2v[ct]);
                if (d2 <= thr[rt][reg]) {
                    unsigned rloc = wave * 32 + rt * 16 + (lane >> 4) * 4 + reg;
                    unsigned col  = cg * 128 + ct * 16 + (lane & 15);
                    unsigned idx = atomicAdd(&cnt, 1u);
                    if (idx < CAP) buf[idx] = (rloc << 11) | col;
                    else refine_one(x, center, c2, x2g, partial,
                                    rg * 128 + (int)rloc, (int)col);
                }
            }
    __syncthreads();

    // ---- exact refine survivors ----
    unsigned n = cnt; if (n > CAP) n = CAP;
    for (unsigned i = tid; i < n; i += 256) {
        unsigned e = buf[i];
        int rloc = (e >> 11) & 127, col = e & (NK - 1);
        refine_one(x, center, c2, x2g, partial, rg * 128 + rloc, col);
    }
}

// ---------------------------------------------------------------------------
// Merge: one wave per row — read final key, gather center row, write label.
// ---------------------------------------------------------------------------
__global__ __launch_bounds__(256)
void merge(const u64* __restrict__ partial,
           const float* __restrict__ center,
           float* __restrict__ out,
           float* __restrict__ label_out) {
    const long row  = (long)blockIdx.x * 4 + (threadIdx.x >> 6);
    const int  lane = threadIdx.x & 63;
    u64 b = partial[row];
    int bk = (int)(b & 0xffffffffULL);
    float2 cv = ((const float2*)(center + (long)bk * ND))[lane];
    ((float2*)(out + row * ND))[lane] = cv;
    if (lane == 0) label_out[row] = (float)bk;
}

// ---------------------------------------------------------------------------
extern "C" void kernel_launch(void* const* d_in, const int* in_sizes, int n_in,
                              void* d_out, int out_size, void* d_ws, size_t ws_size,
                              hipStream_t stream) {
    const float* x      = (const float*)d_in[0];   // [B][D]
    const float* center = (const float*)d_in[1];   // [K][D]
    float* out = (float*)d_out;

    float* out_x      = out;                        // [B*D]
    float* out_center = out + (long)NB * ND;        // [K*D]
    float* out_label  = out_center + (long)NK * ND; // [B]

    // Workspace: xbf[B*D]u16 (4MB), cbf[K*D]u16 (0.5MB), partial[B]u64,
    // c2[K]f32, x2[B]f32   (~4.8 MB)
    unsigned short* xbf = (unsigned short*)d_ws;
    unsigned short* cbf = xbf + (size_t)NB * ND;
    u64*   partial = (u64*)(cbf + (size_t)NK * ND);
    float* c2 = (float*)(partial + NB);
    float* x2 = c2 + NK;

    prep<<<5512, 256, 0, stream>>>(x, center, xbf, cbf, c2, x2, partial,
                                   out_center);
    kmeans_main<<<2048, 256, 0, stream>>>(xbf, cbf, c2, x2, x, center, partial);
    merge<<<NB / 4, 256, 0, stream>>>(partial, center, out_x, out_label);
}

// Round 8
// 120.944 us; speedup vs baseline: 1.6899x; 1.6899x over previous
//
#include <hip/hip_runtime.h>
#include <cstdint>

// B=16384 rows, K=2048 centers, D=128, T=1.0
// Outputs (flat, f32): out[B*D], center[K*D], label[B]
#define NB 16384
#define NK 2048
#define ND 128
#define MARGIN 0.10f
#define CAP 2048
#define XPITCH 132   // padded LDS x-row stride (floats)

typedef __attribute__((ext_vector_type(8))) short bf16x8;
typedef __attribute__((ext_vector_type(4))) float f32x4;
typedef unsigned long long u64;

__device__ __forceinline__ unsigned short f2bf(float f) {
    unsigned u = __float_as_uint(f);
    u += 0x7fffu + ((u >> 16) & 1u);          // round-to-nearest-even
    return (unsigned short)(u >> 16);
}

// ---------------------------------------------------------------------------
// Prep (456 blocks):
//  [0,128)    cbf: center -> bf16 MFMA B-frag layout (R4-validated)
//  [128,136)  c2 (R1-identical chain)
//  [136,392)  center passthrough copy (float4)
//  [392,456)  partial[B] init to ~0
// ---------------------------------------------------------------------------
__global__ __launch_bounds__(256)
void prep(const float* __restrict__ c,
          unsigned short* __restrict__ cbf,
          float* __restrict__ c2,
          float* __restrict__ out_center,
          u64* __restrict__ partial) {
    const int bid = blockIdx.x;
    const int tid = threadIdx.x;
    if (bid < 128) {
        int t = bid * 256 + tid;              // 0..32767
        int lane = t & 63, s = (t >> 6) & 3, kt = t >> 8;
        int kc = kt * 16 + (lane & 15);
        int d0 = s * 32 + (lane >> 4) * 8;
        const float* src = c + (long)kc * ND + d0;
        unsigned short h[8];
#pragma unroll
        for (int j = 0; j < 8; ++j) h[j] = f2bf(src[j]);
        int4 pk;
        pk.x = h[0] | (h[1] << 16); pk.y = h[2] | (h[3] << 16);
        pk.z = h[4] | (h[5] << 16); pk.w = h[6] | (h[7] << 16);
        ((int4*)cbf)[t] = pk;
    } else if (bid < 136) {
        int k = (bid - 128) * 256 + tid;      // 0..2047
        const float4* row = (const float4*)(c + (long)k * ND);
        float s = 0.f;
#pragma unroll 8
        for (int i = 0; i < ND / 4; ++i) {
            float4 v = row[i];
            s += v.x * v.x + v.y * v.y + v.z * v.z + v.w * v.w;
        }
        c2[k] = s;
    } else if (bid < 392) {
        int i = (bid - 136) * 256 + tid;      // 0..K*D/4-1
        ((float4*)out_center)[i] = ((const float4*)c)[i];
    } else {
        int i = (bid - 392) * 256 + tid;      // 0..NB-1
        partial[i] = ~0ULL;
    }
}

// ---------------------------------------------------------------------------
// Main: 2048 blocks (rg 0..511 x ks 0..3) x 256 threads. Block = 32 rows x
// 512 k; wave w covers k in [ks*512 + w*128, +128) ONCE with acc[2][8] kept
// live. Block-min (over the block's 512 k) + MARGIN is a superset threshold
// for the true winner (true argmin is the min of its own subset); candidates
// collected from live accs, exact-refined with the R1-identical fp32 chain,
// combined globally via u64 atomicMin (tie -> lowest k).
// ---------------------------------------------------------------------------
__global__ __launch_bounds__(256)
void kmeans_main(const float* __restrict__ x,
                 const float* __restrict__ center,
                 const unsigned short* __restrict__ cbf,
                 const float* __restrict__ c2,
                 u64* __restrict__ partial) {
    __shared__ float xs[32 * XPITCH];          // 16.9 KB fp32 x rows
    __shared__ float x2s[32];
    __shared__ unsigned bmin[32];
    __shared__ unsigned buf[CAP];              // 8 KB candidates
    __shared__ unsigned cnt;

    const int tid  = threadIdx.x;
    const int lane = tid & 63;
    const int wave = __builtin_amdgcn_readfirstlane(tid >> 6);  // 0..3
    const int rg = blockIdx.x >> 2;            // row-group (32 rows)
    const int ks = blockIdx.x & 3;             // k-split (512 k)
    const long rb = (long)rg * 32;

    // ---- stage x rows -> LDS (coalesced, 16 floats/thread) ----
    {
        int r = tid >> 3, q = tid & 7;
        const float4* src = (const float4*)(x + (rb + r) * ND + q * 16);
        float4 v0 = src[0], v1 = src[1], v2 = src[2], v3 = src[3];
        float* dst = xs + r * XPITCH + q * 16;
        ((float4*)dst)[0] = v0; ((float4*)dst)[1] = v1;
        ((float4*)dst)[2] = v2; ((float4*)dst)[3] = v3;
    }
    if (tid < 32) bmin[tid] = 0x7f800000u;
    if (tid == 0) cnt = 0;
    __syncthreads();

    // ---- x2 per row: chain IDENTICAL to R1 (float2, 6-level butterfly) ----
    for (int i = 0; i < 8; ++i) {
        int r = wave * 8 + i;
        float2 v = *(const float2*)(xs + r * XPITCH + lane * 2);
        float s = v.x * v.x + v.y * v.y;
#pragma unroll
        for (int off = 32; off; off >>= 1) s += __shfl_xor(s, off, 64);
        if (lane == 0) x2s[r] = s;
    }
    __syncthreads();

    // ---- A-frags (2 row-tiles) from LDS, f2bf (R5-validated) ----
    bf16x8 af[2][4];
#pragma unroll
    for (int rt = 0; rt < 2; ++rt)
#pragma unroll
        for (int s = 0; s < 4; ++s) {
            const float* p = xs + (rt * 16 + (lane & 15)) * XPITCH
                               + s * 32 + (lane >> 4) * 8;
            float4 u0 = ((const float4*)p)[0];
            float4 u1 = ((const float4*)p)[1];
            bf16x8 a;
            a[0] = (short)f2bf(u0.x); a[1] = (short)f2bf(u0.y);
            a[2] = (short)f2bf(u0.z); a[3] = (short)f2bf(u0.w);
            a[4] = (short)f2bf(u1.x); a[5] = (short)f2bf(u1.y);
            a[6] = (short)f2bf(u1.z); a[7] = (short)f2bf(u1.w);
            af[rt][s] = a;
        }

    float x2p[2][4];
#pragma unroll
    for (int rt = 0; rt < 2; ++rt)
#pragma unroll
        for (int reg = 0; reg < 4; ++reg)
            x2p[rt][reg] = x2s[rt * 16 + (lane >> 4) * 4 + reg];

    // ---- one sweep: 8 k-tiles, acc kept live ----
    const bf16x8* CF = (const bf16x8*)cbf;
    const int kt0 = ks * 32 + wave * 8;        // wave's first 16-k tile

    f32x4 acc[2][8];
#pragma unroll
    for (int rt = 0; rt < 2; ++rt)
#pragma unroll
        for (int ct = 0; ct < 8; ++ct) acc[rt][ct] = (f32x4){0.f, 0.f, 0.f, 0.f};

#pragma unroll
    for (int ct = 0; ct < 8; ++ct) {
        const int kt = kt0 + ct;
#pragma unroll
        for (int s = 0; s < 4; ++s) {
            bf16x8 b = CF[(kt * 4 + s) * 64 + lane];
            acc[0][ct] = __builtin_amdgcn_mfma_f32_16x16x32_bf16(af[0][s], b, acc[0][ct], 0, 0, 0);
            acc[1][ct] = __builtin_amdgcn_mfma_f32_16x16x32_bf16(af[1][s], b, acc[1][ct], 0, 0, 0);
        }
    }

    float c2v[8];
#pragma unroll
    for (int ct = 0; ct < 8; ++ct)
        c2v[ct] = c2[(kt0 + ct) * 16 + (lane & 15)];

    // ---- block-min per row (clamped >=0 so uint order works) ----
    float rmin[2][4];
#pragma unroll
    for (int rt = 0; rt < 2; ++rt)
#pragma unroll
        for (int reg = 0; reg < 4; ++reg) rmin[rt][reg] = __builtin_inff();
#pragma unroll
    for (int rt = 0; rt < 2; ++rt)
#pragma unroll
        for (int ct = 0; ct < 8; ++ct)
#pragma unroll
            for (int reg = 0; reg < 4; ++reg) {
                float d2 = fmaf(-2.f, acc[rt][ct][reg], x2p[rt][reg] + c2v[ct]);
                rmin[rt][reg] = fminf(rmin[rt][reg], d2);
            }
#pragma unroll
    for (int rt = 0; rt < 2; ++rt)
#pragma unroll
        for (int reg = 0; reg < 4; ++reg) {
            float v = rmin[rt][reg];
#pragma unroll
            for (int off = 1; off < 16; off <<= 1)
                v = fminf(v, __shfl_xor(v, off, 64));
            if ((lane & 15) == 0)
                atomicMin(&bmin[rt * 16 + (lane >> 4) * 4 + reg],
                          __float_as_uint(fmaxf(v, 0.f)));
        }
    __syncthreads();

    // ---- collect candidates from live accs vs block threshold ----
    float thr[2][4];
#pragma unroll
    for (int rt = 0; rt < 2; ++rt)
#pragma unroll
        for (int reg = 0; reg < 4; ++reg)
            thr[rt][reg] = __uint_as_float(
                bmin[rt * 16 + (lane >> 4) * 4 + reg]) + MARGIN;

#pragma unroll
    for (int rt = 0; rt < 2; ++rt)
#pragma unroll
        for (int ct = 0; ct < 8; ++ct)
#pragma unroll
            for (int reg = 0; reg < 4; ++reg) {
                float d2 = fmaf(-2.f, acc[rt][ct][reg], x2p[rt][reg] + c2v[ct]);
                if (d2 <= thr[rt][reg]) {
                    unsigned rloc = rt * 16 + (lane >> 4) * 4 + reg;
                    unsigned col  = (unsigned)((kt0 + ct) * 16 + (lane & 15));
                    unsigned idx = atomicAdd(&cnt, 1u);
                    if (idx < CAP) buf[idx] = (rloc << 11) | col;
                }
            }
    __syncthreads();

    // ---- exact refine: fp32 chain IDENTICAL to R1 (x from LDS) ----
    unsigned n = cnt; if (n > CAP) n = CAP;
    for (unsigned i = tid; i < n; i += 256) {
        unsigned e = buf[i];
        int rloc = (e >> 11) & 31, col = e & (NK - 1);
        const float* xr = xs + rloc * XPITCH;
        const float* cr = center + (long)col * ND;
        float dot = 0.f;
#pragma unroll 8
        for (int d = 0; d < ND; ++d) dot = fmaf(xr[d], cr[d], dot);
        float t = x2s[rloc] + c2[col];
        float f = fmaxf(fmaf(-2.0f, dot, t), 0.0f);
        float s = __builtin_sqrtf(f);
        u64 key = ((u64)__float_as_uint(s) << 32) | (unsigned)col;
        atomicMin(&partial[rb + rloc], key);
    }
}

// ---------------------------------------------------------------------------
// Merge: one wave per row — read final key, gather center row, write label.
// ---------------------------------------------------------------------------
__global__ __launch_bounds__(256)
void merge(const u64* __restrict__ partial,
           const float* __restrict__ center,
           float* __restrict__ out,
           float* __restrict__ label_out) {
    const long row  = (long)blockIdx.x * 4 + (threadIdx.x >> 6);
    const int  lane = threadIdx.x & 63;
    u64 b = partial[row];
    int bk = (int)(b & 0xffffffffULL);
    float2 cv = ((const float2*)(center + (long)bk * ND))[lane];
    ((float2*)(out + row * ND))[lane] = cv;
    if (lane == 0) label_out[row] = (float)bk;
}

// ---------------------------------------------------------------------------
extern "C" void kernel_launch(void* const* d_in, const int* in_sizes, int n_in,
                              void* d_out, int out_size, void* d_ws, size_t ws_size,
                              hipStream_t stream) {
    const float* x      = (const float*)d_in[0];   // [B][D]
    const float* center = (const float*)d_in[1];   // [K][D]
    float* out = (float*)d_out;

    float* out_x      = out;                        // [B*D]
    float* out_center = out + (long)NB * ND;        // [K*D]
    float* out_label  = out_center + (long)NK * ND; // [B]

    // Workspace: cbf[K*D]u16 (0.5MB), c2[K]f32, partial[B]u64 (~0.64MB)
    unsigned short* cbf = (unsigned short*)d_ws;
    float* c2 = (float*)(cbf + (size_t)NK * ND);
    u64* partial = (u64*)(c2 + NK);

    prep<<<456, 256, 0, stream>>>(center, cbf, c2, out_center, partial);
    kmeans_main<<<2048, 256, 0, stream>>>(x, center, cbf, c2, partial);
    merge<<<NB / 4, 256, 0, stream>>>(partial, center, out_x, out_label);
}